// Round 20
// baseline (6974.857 us; speedup 1.0000x reference)
//
#include <hip/hip_runtime.h>
#include <stdint.h>

#define T_TOK 8192
#define DIM   2048
#define NEXP  16
#define NLAY  4
#define TOPK  8

#define BM 128
#define BK 32
#define NT 64

typedef _Float16 f16;
typedef f16   f16x8 __attribute__((ext_vector_type(8)));
typedef f16   f16x4 __attribute__((ext_vector_type(4)));
typedef float f32x4 __attribute__((ext_vector_type(4)));
typedef float fv4   __attribute__((ext_vector_type(4)));

// ---------------- routing: fp32 logits, softmax, exact top-8 ----------------
__global__ __launch_bounds__(256) void route_kernel(
    const float* __restrict__ h, const float* __restrict__ gw,
    int* __restrict__ cnt, int* __restrict__ tok, float* __restrict__ wt)
{
  int gid  = blockIdx.x * 256 + threadIdx.x;
  int t    = gid >> 6;
  int lane = threadIdx.x & 63;
  if (t >= T_TOK) return;
  const float* hr = h + (size_t)t * DIM;
  float hreg[32];
#pragma unroll
  for (int j = 0; j < 32; ++j) hreg[j] = hr[lane + 64 * j];
  float p[16];
#pragma unroll
  for (int e = 0; e < 16; ++e) {
    const float* gr = gw + e * DIM;
    float s = 0.f;
#pragma unroll
    for (int j = 0; j < 32; ++j) s += hreg[j] * gr[lane + 64 * j];
#pragma unroll
    for (int off = 32; off; off >>= 1) s += __shfl_xor(s, off);
    p[e] = s;
  }
  float mx = p[0];
#pragma unroll
  for (int e = 1; e < 16; ++e) mx = fmaxf(mx, p[e]);
  float sum = 0.f;
#pragma unroll
  for (int e = 0; e < 16; ++e) { p[e] = expf(p[e] - mx); sum += p[e]; }
  float inv = 1.f / sum;
#pragma unroll
  for (int e = 0; e < 16; ++e) p[e] *= inv;
  if (lane < 16) {
    float mine = p[lane];
    int rank = 0;
#pragma unroll
    for (int j = 0; j < 16; ++j)
      rank += (p[j] > mine) || (p[j] == mine && j < lane);  // jax top_k tie-break
    if (rank < TOPK) {
      int pos = atomicAdd(&cnt[lane], 1);
      tok[lane * T_TOK + pos] = t;
      wt [lane * T_TOK + pos] = mine;
    }
  }
}

// ------- A: fp32 -> scaled fp16 hi/lo split (x*64 = hi + lo), row-major -----
__global__ __launch_bounds__(256) void split_kernel(
    const float* __restrict__ src, f16* __restrict__ hi, f16* __restrict__ lo, int n4)
{
  int i0 = blockIdx.x * 256 + threadIdx.x;
  int stride = gridDim.x * 256;
  for (int i = i0; i < n4; i += stride) {
    fv4 v = ((const fv4*)src)[i];
    f16x4 h4, l4;
#pragma unroll
    for (int j = 0; j < 4; ++j) {
      float x = v[j] * 64.f;       // pre-scale keeps lo parts out of fp16 denormal range
      f16 hh = (f16)x;
      h4[j] = hh;
      l4[j] = (f16)(x - (float)hh);
    }
    ((f16x4*)hi)[i] = h4;
    ((f16x4*)lo)[i] = l4;
  }
}

// ------- W: split + transpose to K-major-16B layout [E][K/8][2048][8] -------
__global__ __launch_bounds__(256) void wsplit_kernel(
    const float* __restrict__ src, f16* __restrict__ hi, f16* __restrict__ lo)
{
  const int eidx = blockIdx.z;
  const int r0   = blockIdx.y * 32;
  const int k0   = blockIdx.x * 64;
  __shared__ f16 th[32 * 9 * 8];   // [32 rows][9 chunk-slots (pad)][8 f16]
  __shared__ f16 tl[32 * 9 * 8];
  const int rr = threadIdx.x >> 3, c8 = threadIdx.x & 7;
  const float* s = src + ((size_t)eidx * DIM + r0 + rr) * DIM + k0 + c8 * 8;
  fv4 v0 = *(const fv4*)s;
  fv4 v1 = *(const fv4*)(s + 4);
  f16x8 hv, lv;
#pragma unroll
  for (int j = 0; j < 4; ++j) {
    float x = v0[j] * 64.f; f16 hh = (f16)x; hv[j] = hh; lv[j] = (f16)(x - (float)hh);
    float y = v1[j] * 64.f; f16 h2 = (f16)y; hv[4 + j] = h2; lv[4 + j] = (f16)(y - (float)h2);
  }
  *(f16x8*)&th[(rr * 9 + c8) * 8] = hv;
  *(f16x8*)&tl[(rr * 9 + c8) * 8] = lv;
  __syncthreads();
  const int c8w = threadIdx.x >> 5, rw = threadIdx.x & 31;
  f16x8 oh = *(const f16x8*)&th[(rw * 9 + c8w) * 8];
  f16x8 ol = *(const f16x8*)&tl[(rw * 9 + c8w) * 8];
  size_t o = (((size_t)eidx * (DIM / 8) + (k0 / 8 + c8w)) * DIM + r0 + rw) * 8;
  *(f16x8*)&hi[o] = oh;
  *(f16x8*)&lo[o] = ol;
}

// --- 3-term gathered grouped GEMM (layers 0-2), 128x128, 3 blocks/CU --------
// gemm1's proven 3-domain geometry with the 3-term inner loop: same staged
// bytes per kt-progress as the BN=256/2-block config, but 3 desync barrier
// domains (3/2/1-domain ladder measured 51/50/32% util). R16-gemm1 schedule:
// no order pins (TLP-covered regime), w2F read after barrier from dbuf'd W2.
// LDS 48 KB (A1,A2 single 16 + W1,W2 dbuf 32) x3 = 144 <= 160 KB.
__global__ __launch_bounds__(256, 3) void moe_gemm3(
    const f16* __restrict__ A1, const f16* __restrict__ A2,
    const f16* __restrict__ W1t, const f16* __restrict__ W2t,
    const int* __restrict__ tok, const float* __restrict__ wt,
    const int* __restrict__ cnt, float* __restrict__ out)
{
  // b = 512p + 8q + r -> group w = 8p + r (w = e*16 + nt, XCD = r), my = q
  const int b  = blockIdx.x;
  const int w  = (b >> 9) * 8 + (b & 7);   // 0..255
  const int my = (b >> 3) & 63;            // 0..63
  const int e  = w >> 4;
  const int ce = cnt[e];
  const int m0 = my * BM;
  if (m0 >= ce) return;
  const int n0 = (w & 15) * 128;

  __shared__ f16 lsA1[BM * BK];        // [128 row][4 chunk][8], 8 KB single-buf
  __shared__ f16 lsA2[BM * BK];
  __shared__ f16 lsW1[2][128 * BK];    // [4 kc][128 row][8], 2 x 8 KB dbuf
  __shared__ f16 lsW2[2][128 * BK];

  const int tid = threadIdx.x;   // 0..255

  // A staging row-major: slots {tid, tid+256}; slot s -> row s>>2, phys chunk
  // s&3, global chunk gc = (s&3)^((row>>1)&3) (involution; rows r, r+64 match).
  const int ar0 = tid >> 2;            // 0..63
  const int gc  = (tid & 3) ^ ((ar0 >> 1) & 3);
  const size_t aofs0 = (size_t)tok[e * T_TOK + min(m0 + ar0,      ce - 1)] * DIM + gc * 8;
  const size_t aofs1 = (size_t)tok[e * T_TOK + min(m0 + ar0 + 64, ce - 1)] * DIM + gc * 8;
  // W staging K-major: slot s = tid + 256j: kc = s>>7 (+2 for slot1), row = s&127.
  const int wrow = tid & 127;
  const int wkc  = tid >> 7;           // 0..1
  const size_t wbase = (size_t)e * (DIM / 8) * DIM * 8 + ((size_t)n0 + wrow) * 8;

  auto stageA = [&](int kt) {
    const int k0 = kt * BK;
    __builtin_amdgcn_global_load_lds(
        (const __attribute__((address_space(1))) void*)(A1 + aofs0 + k0),
        (__attribute__((address_space(3))) void*)(&lsA1[tid * 8]), 16, 0, 0);
    __builtin_amdgcn_global_load_lds(
        (const __attribute__((address_space(1))) void*)(A1 + aofs1 + k0),
        (__attribute__((address_space(3))) void*)(&lsA1[(tid + 256) * 8]), 16, 0, 0);
    __builtin_amdgcn_global_load_lds(
        (const __attribute__((address_space(1))) void*)(A2 + aofs0 + k0),
        (__attribute__((address_space(3))) void*)(&lsA2[tid * 8]), 16, 0, 0);
    __builtin_amdgcn_global_load_lds(
        (const __attribute__((address_space(1))) void*)(A2 + aofs1 + k0),
        (__attribute__((address_space(3))) void*)(&lsA2[(tid + 256) * 8]), 16, 0, 0);
  };
  auto stageW = [&](int kt, int bb) {
    const int kc0 = kt * 4;
    __builtin_amdgcn_global_load_lds(
        (const __attribute__((address_space(1))) void*)(W1t + wbase + (size_t)(kc0 + wkc) * DIM * 8),
        (__attribute__((address_space(3))) void*)(&lsW1[bb][tid * 8]), 16, 0, 0);
    __builtin_amdgcn_global_load_lds(
        (const __attribute__((address_space(1))) void*)(W1t + wbase + (size_t)(kc0 + wkc + 2) * DIM * 8),
        (__attribute__((address_space(3))) void*)(&lsW1[bb][(tid + 256) * 8]), 16, 0, 0);
    __builtin_amdgcn_global_load_lds(
        (const __attribute__((address_space(1))) void*)(W2t + wbase + (size_t)(kc0 + wkc) * DIM * 8),
        (__attribute__((address_space(3))) void*)(&lsW2[bb][tid * 8]), 16, 0, 0);
    __builtin_amdgcn_global_load_lds(
        (const __attribute__((address_space(1))) void*)(W2t + wbase + (size_t)(kc0 + wkc + 2) * DIM * 8),
        (__attribute__((address_space(3))) void*)(&lsW2[bb][(tid + 256) * 8]), 16, 0, 0);
  };

  const int lane = tid & 63;
  const int wid  = tid >> 6;
  const int wm   = wid & 1;           // M half (64 rows)
  const int wn   = wid >> 1;          // N half (64 cols)
  const int lr   = lane & 15;
  const int lk   = lane >> 4;         // 0..3 -> k-chunk
  const int aswz = lk ^ ((lr >> 1) & 3);  // phys chunk holding logical lk

  f32x4 acc[4][4];
#pragma unroll
  for (int i = 0; i < 4; ++i)
#pragma unroll
    for (int j = 0; j < 4; ++j)
      acc[i][j] = (f32x4){0.f, 0.f, 0.f, 0.f};

  stageA(0);
  stageW(0, 0);
  asm volatile("s_waitcnt vmcnt(0)" ::: "memory");
  __builtin_amdgcn_s_barrier();
  __builtin_amdgcn_sched_barrier(0);

  int cur = 0;
  for (int kt = 0; kt < NT; ++kt) {
    const bool pf = (kt + 1 < NT);
    f16x8 a1F[4], a2F[4], w1F[4], w2F[4];

    // ---- read A frags + W1 frags from current buffers
#pragma unroll
    for (int mi = 0; mi < 4; ++mi) {
      int r = wm * 64 + mi * 16 + lr;
      a1F[mi] = *(const f16x8*)&lsA1[r * 32 + aswz * 8];
      a2F[mi] = *(const f16x8*)&lsA2[r * 32 + aswz * 8];
    }
#pragma unroll
    for (int ni = 0; ni < 4; ++ni) {
      int off = (lk * 128 + wn * 64 + ni * 16 + lr) * 8;
      w1F[ni] = *(const f16x8*)&lsW1[cur][off];
    }
    asm volatile("s_waitcnt lgkmcnt(0)" ::: "memory");
    __builtin_amdgcn_sched_barrier(0);
    __builtin_amdgcn_s_barrier();                        // lsA free
    __builtin_amdgcn_sched_barrier(0);
    if (pf) { stageA(kt + 1); stageW(kt + 1, cur ^ 1); }

    // w2F from dbuf'd W2[cur] (not overwritten); rides under cluster 0-1
#pragma unroll
    for (int ni = 0; ni < 4; ++ni) {
      int off = (lk * 128 + wn * 64 + ni * 16 + lr) * 8;
      w2F[ni] = *(const f16x8*)&lsW2[cur][off];
    }

    __builtin_amdgcn_s_setprio(1);
#pragma unroll
    for (int mi = 0; mi < 4; ++mi)
#pragma unroll
      for (int ni = 0; ni < 4; ++ni)
        acc[mi][ni] = __builtin_amdgcn_mfma_f32_16x16x32_f16(a1F[mi], w1F[ni], acc[mi][ni], 0, 0, 0);
#pragma unroll
    for (int mi = 0; mi < 4; ++mi)
#pragma unroll
      for (int ni = 0; ni < 4; ++ni)
        acc[mi][ni] = __builtin_amdgcn_mfma_f32_16x16x32_f16(a2F[mi], w1F[ni], acc[mi][ni], 0, 0, 0);
#pragma unroll
    for (int mi = 0; mi < 4; ++mi)
#pragma unroll
      for (int ni = 0; ni < 4; ++ni)
        acc[mi][ni] = __builtin_amdgcn_mfma_f32_16x16x32_f16(a1F[mi], w2F[ni], acc[mi][ni], 0, 0, 0);
    __builtin_amdgcn_s_setprio(0);

    if (pf) {
      asm volatile("s_waitcnt vmcnt(0)" ::: "memory");   // kt+1 stage landed
      __builtin_amdgcn_s_barrier();
      __builtin_amdgcn_sched_barrier(0);
    }
    cur ^= 1;
  }

  // epilogue: out[tok, n] += w * acc / 4096  (descale 64*64)
  const int ebase = e * T_TOK;
#pragma unroll
  for (int mi = 0; mi < 4; ++mi) {
#pragma unroll
    for (int q = 0; q < 4; ++q) {
      int pos = m0 + wm * 64 + mi * 16 + lk * 4 + q;
      if (pos < ce) {
        int tt = tok[ebase + pos];
        float sc = wt[ebase + pos] * (1.0f / 4096.0f);
        float* orow = out + (size_t)tt * DIM + n0 + wn * 64;
#pragma unroll
        for (int ni = 0; ni < 4; ++ni)
          atomicAdd(&orow[ni * 16 + lr], sc * acc[mi][ni][q]);
      }
    }
  }
}

// --- 1-term GEMM (final layer), 128x128, 3 blocks/CU (R16 body, measured) ---
__global__ __launch_bounds__(256, 3) void moe_gemm1(
    const f16* __restrict__ A1,
    const f16* __restrict__ W1t,
    const int* __restrict__ tok, const float* __restrict__ wt,
    const int* __restrict__ cnt, float* __restrict__ out)
{
  const int b  = blockIdx.x;
  const int w  = (b >> 9) * 8 + (b & 7);   // 0..255
  const int my = (b >> 3) & 63;            // 0..63
  const int e  = w >> 4;
  const int ce = cnt[e];
  const int m0 = my * BM;
  if (m0 >= ce) return;
  const int n0 = (w & 15) * 128;

  __shared__ f16 lsA1[BM * BK];        // 8 KB single-buf, row-major
  __shared__ f16 lsW1[2][128 * BK];    // [4 kc][128 row][8], 2 x 8 KB dbuf

  const int tid = threadIdx.x;
  const int ar0 = tid >> 2;
  const int gc  = (tid & 3) ^ ((ar0 >> 1) & 3);
  const size_t aofs0 = (size_t)tok[e * T_TOK + min(m0 + ar0,      ce - 1)] * DIM + gc * 8;
  const size_t aofs1 = (size_t)tok[e * T_TOK + min(m0 + ar0 + 64, ce - 1)] * DIM + gc * 8;
  const int wrow = tid & 127;
  const int wkc  = tid >> 7;           // 0..1; slot1 kc += 2
  const size_t wbase = (size_t)e * (DIM / 8) * DIM * 8 + ((size_t)n0 + wrow) * 8;

  auto stageA = [&](int kt) {
    const int k0 = kt * BK;
    __builtin_amdgcn_global_load_lds(
        (const __attribute__((address_space(1))) void*)(A1 + aofs0 + k0),
        (__attribute__((address_space(3))) void*)(&lsA1[tid * 8]), 16, 0, 0);
    __builtin_amdgcn_global_load_lds(
        (const __attribute__((address_space(1))) void*)(A1 + aofs1 + k0),
        (__attribute__((address_space(3))) void*)(&lsA1[(tid + 256) * 8]), 16, 0, 0);
  };
  auto stageW = [&](int kt, int bb) {
    const int kc0 = kt * 4;
    __builtin_amdgcn_global_load_lds(
        (const __attribute__((address_space(1))) void*)(W1t + wbase + (size_t)(kc0 + wkc) * DIM * 8),
        (__attribute__((address_space(3))) void*)(&lsW1[bb][tid * 8]), 16, 0, 0);
    __builtin_amdgcn_global_load_lds(
        (const __attribute__((address_space(1))) void*)(W1t + wbase + (size_t)(kc0 + wkc + 2) * DIM * 8),
        (__attribute__((address_space(3))) void*)(&lsW1[bb][(tid + 256) * 8]), 16, 0, 0);
  };

  const int lane = tid & 63;
  const int wid  = tid >> 6;
  const int wm   = wid & 1;           // M half (64 rows)
  const int wn   = wid >> 1;          // N half (64 cols)
  const int lr   = lane & 15;
  const int lk   = lane >> 4;
  const int aswz = lk ^ ((lr >> 1) & 3);

  f32x4 acc[4][4];
#pragma unroll
  for (int i = 0; i < 4; ++i)
#pragma unroll
    for (int j = 0; j < 4; ++j)
      acc[i][j] = (f32x4){0.f, 0.f, 0.f, 0.f};

  stageA(0);
  stageW(0, 0);
  asm volatile("s_waitcnt vmcnt(0)" ::: "memory");
  __builtin_amdgcn_s_barrier();
  __builtin_amdgcn_sched_barrier(0);

  int cur = 0;
  for (int kt = 0; kt < NT; ++kt) {
    const bool pf = (kt + 1 < NT);
    f16x8 a1F[4], w1F[4];

#pragma unroll
    for (int mi = 0; mi < 4; ++mi) {
      int r = wm * 64 + mi * 16 + lr;
      a1F[mi] = *(const f16x8*)&lsA1[r * 32 + aswz * 8];
    }
#pragma unroll
    for (int ni = 0; ni < 4; ++ni) {
      int off = (lk * 128 + wn * 64 + ni * 16 + lr) * 8;
      w1F[ni] = *(const f16x8*)&lsW1[cur][off];
    }
    asm volatile("s_waitcnt lgkmcnt(0)" ::: "memory");
    __builtin_amdgcn_sched_barrier(0);
    __builtin_amdgcn_s_barrier();
    __builtin_amdgcn_sched_barrier(0);
    if (pf) { stageA(kt + 1); stageW(kt + 1, cur ^ 1); }

    __builtin_amdgcn_s_setprio(1);
#pragma unroll
    for (int mi = 0; mi < 4; ++mi)
#pragma unroll
      for (int ni = 0; ni < 4; ++ni)
        acc[mi][ni] = __builtin_amdgcn_mfma_f32_16x16x32_f16(a1F[mi], w1F[ni], acc[mi][ni], 0, 0, 0);
    __builtin_amdgcn_s_setprio(0);

    if (pf) {
      asm volatile("s_waitcnt vmcnt(0)" ::: "memory");
      __builtin_amdgcn_s_barrier();
      __builtin_amdgcn_sched_barrier(0);
    }
    cur ^= 1;
  }

  const int ebase = e * T_TOK;
#pragma unroll
  for (int mi = 0; mi < 4; ++mi) {
#pragma unroll
    for (int q = 0; q < 4; ++q) {
      int pos = m0 + wm * 64 + mi * 16 + lk * 4 + q;
      if (pos < ce) {
        int tt = tok[ebase + pos];
        float sc = wt[ebase + pos] * (1.0f / 4096.0f);
        float* orow = out + (size_t)tt * DIM + n0 + wn * 64;
#pragma unroll
        for (int ni = 0; ni < 4; ++ni)
          atomicAdd(&orow[ni * 16 + lr], sc * acc[mi][ni][q]);
      }
    }
  }
}

// ------------------------------- launcher -----------------------------------
extern "C" void kernel_launch(void* const* d_in, const int* in_sizes, int n_in,
                              void* d_out, int out_size, void* d_ws, size_t ws_size,
                              hipStream_t stream) {
  const float* x  = (const float*)d_in[0];
  const float* gw = (const float*)d_in[1];
  const float* ew = (const float*)d_in[2];
  float* out = (float*)d_out;

  char* ws = (char*)d_ws;
  float* hA  = (float*)ws;                        // 64 MB fp32 h ping buffer
  f16*   A1  = (f16*)(ws + 67108864ull);          // 32 MB
  f16*   A2  = (f16*)(ws + 100663296ull);         // 32 MB
  f16*   W1t = (f16*)(ws + 134217728ull);         // 128 MB (K-major, this layer)
  f16*   W2t = (f16*)(ws + 268435456ull);         // 128 MB
  int*   tok = (int*)(ws + 402653184ull);         // 512 KB
  float* wt  = (float*)(ws + 403177472ull);       // 512 KB
  int*   cnt = (int*)(ws + 403701760ull);         // 64 B

  const float* hin = x;
  float* houts[4] = {hA, out, hA, out};           // ping-pong; final layer -> d_out
  for (int l = 0; l < NLAY; ++l) {
    float* hout = houts[l];
    hipMemsetAsync(cnt, 0, 64, stream);
    route_kernel<<<T_TOK / 4, 256, 0, stream>>>(hin, gw + (size_t)l * NEXP * DIM, cnt, tok, wt);
    split_kernel<<<4096, 256, 0, stream>>>(hin, A1, A2, T_TOK * DIM / 4);
    {
      dim3 gt(DIM / 64, DIM / 32, NEXP);
      wsplit_kernel<<<gt, 256, 0, stream>>>(ew + (size_t)l * NEXP * DIM * DIM, W1t, W2t);
    }
    hipMemsetAsync(hout, 0, (size_t)T_TOK * DIM * 4, stream);
    if (l < NLAY - 1)
      moe_gemm3<<<16 * 64 * 16, 256, 0, stream>>>(A1, A2, W1t, W2t, tok, wt, cnt, hout);
    else
      moe_gemm1<<<16 * 64 * 16, 256, 0, stream>>>(A1, W1t, tok, wt, cnt, hout);
    hin = hout;
  }
}

// Round 21
// 5996.511 us; speedup vs baseline: 1.1632x; 1.1632x over previous
//
#include <hip/hip_runtime.h>
#include <stdint.h>

#define T_TOK 8192
#define DIM   2048
#define NEXP  16
#define NLAY  4
#define TOPK  8

#define BM 128
#define BN 256
#define BK 32
#define NT 64

typedef _Float16 f16;
typedef f16   f16x8 __attribute__((ext_vector_type(8)));
typedef f16   f16x4 __attribute__((ext_vector_type(4)));
typedef float f32x4 __attribute__((ext_vector_type(4)));
typedef float fv4   __attribute__((ext_vector_type(4)));

// ---------------- routing: fp32 logits, softmax, exact top-8 ----------------
__global__ __launch_bounds__(256) void route_kernel(
    const float* __restrict__ h, const float* __restrict__ gw,
    int* __restrict__ cnt, int* __restrict__ tok, float* __restrict__ wt)
{
  int gid  = blockIdx.x * 256 + threadIdx.x;
  int t    = gid >> 6;
  int lane = threadIdx.x & 63;
  if (t >= T_TOK) return;
  const float* hr = h + (size_t)t * DIM;
  float hreg[32];
#pragma unroll
  for (int j = 0; j < 32; ++j) hreg[j] = hr[lane + 64 * j];
  float p[16];
#pragma unroll
  for (int e = 0; e < 16; ++e) {
    const float* gr = gw + e * DIM;
    float s = 0.f;
#pragma unroll
    for (int j = 0; j < 32; ++j) s += hreg[j] * gr[lane + 64 * j];
#pragma unroll
    for (int off = 32; off; off >>= 1) s += __shfl_xor(s, off);
    p[e] = s;
  }
  float mx = p[0];
#pragma unroll
  for (int e = 1; e < 16; ++e) mx = fmaxf(mx, p[e]);
  float sum = 0.f;
#pragma unroll
  for (int e = 0; e < 16; ++e) { p[e] = expf(p[e] - mx); sum += p[e]; }
  float inv = 1.f / sum;
#pragma unroll
  for (int e = 0; e < 16; ++e) p[e] *= inv;
  if (lane < 16) {
    float mine = p[lane];
    int rank = 0;
#pragma unroll
    for (int j = 0; j < 16; ++j)
      rank += (p[j] > mine) || (p[j] == mine && j < lane);  // jax top_k tie-break
    if (rank < TOPK) {
      int pos = atomicAdd(&cnt[lane], 1);
      tok[lane * T_TOK + pos] = t;
      wt [lane * T_TOK + pos] = mine;
    }
  }
}

// ------- A: fp32 -> scaled fp16 hi/lo split (x*64 = hi + lo), row-major -----
__global__ __launch_bounds__(256) void split_kernel(
    const float* __restrict__ src, f16* __restrict__ hi, f16* __restrict__ lo, int n4)
{
  int i0 = blockIdx.x * 256 + threadIdx.x;
  int stride = gridDim.x * 256;
  for (int i = i0; i < n4; i += stride) {
    fv4 v = ((const fv4*)src)[i];
    f16x4 h4, l4;
#pragma unroll
    for (int j = 0; j < 4; ++j) {
      float x = v[j] * 64.f;       // pre-scale keeps lo parts out of fp16 denormal range
      f16 hh = (f16)x;
      h4[j] = hh;
      l4[j] = (f16)(x - (float)hh);
    }
    ((f16x4*)hi)[i] = h4;
    ((f16x4*)lo)[i] = l4;
  }
}

// ------- W: split + transpose to K-major-16B layout [E][K/8][2048][8] -------
__global__ __launch_bounds__(256) void wsplit_kernel(
    const float* __restrict__ src, f16* __restrict__ hi, f16* __restrict__ lo)
{
  const int eidx = blockIdx.z;
  const int r0   = blockIdx.y * 32;
  const int k0   = blockIdx.x * 64;
  __shared__ f16 th[32 * 9 * 8];   // [32 rows][9 chunk-slots (pad)][8 f16]
  __shared__ f16 tl[32 * 9 * 8];
  const int rr = threadIdx.x >> 3, c8 = threadIdx.x & 7;
  const float* s = src + ((size_t)eidx * DIM + r0 + rr) * DIM + k0 + c8 * 8;
  fv4 v0 = *(const fv4*)s;
  fv4 v1 = *(const fv4*)(s + 4);
  f16x8 hv, lv;
#pragma unroll
  for (int j = 0; j < 4; ++j) {
    float x = v0[j] * 64.f; f16 hh = (f16)x; hv[j] = hh; lv[j] = (f16)(x - (float)hh);
    float y = v1[j] * 64.f; f16 h2 = (f16)y; hv[4 + j] = h2; lv[4 + j] = (f16)(y - (float)h2);
  }
  *(f16x8*)&th[(rr * 9 + c8) * 8] = hv;
  *(f16x8*)&tl[(rr * 9 + c8) * 8] = lv;
  __syncthreads();
  const int c8w = threadIdx.x >> 5, rw = threadIdx.x & 31;
  f16x8 oh = *(const f16x8*)&th[(rw * 9 + c8w) * 8];
  f16x8 ol = *(const f16x8*)&tl[(rw * 9 + c8w) * 8];
  size_t o = (((size_t)eidx * (DIM / 8) + (k0 / 8 + c8w)) * DIM + r0 + rw) * 8;
  *(f16x8*)&hi[o] = oh;
  *(f16x8*)&lo[o] = ol;
}

// --- 3-term gathered grouped GEMM (layers 0-2), 128x256, 2 blocks/CU --------
// R17 schedule (best measured):
//  (1) stageW(kt+1) hoisted to loop top -> its 8 loads land under this kt.
//  (2) mid-wait counted lgkmcnt(8): only the 8 A-reads guard the barrier.
__global__ __launch_bounds__(256, 2) void moe_gemm3(
    const f16* __restrict__ A1, const f16* __restrict__ A2,
    const f16* __restrict__ W1t, const f16* __restrict__ W2t,
    const int* __restrict__ tok, const float* __restrict__ wt,
    const int* __restrict__ cnt, float* __restrict__ out)
{
  // b = 512p + 8q + r -> group w = 8p + r (w = e*8 + nt, XCD = nt), my = q
  const int b  = blockIdx.x;
  const int w  = (b >> 9) * 8 + (b & 7);   // 0..127
  const int my = (b >> 3) & 63;            // 0..63
  const int e  = w >> 3;
  const int ce = cnt[e];
  const int m0 = my * BM;
  if (m0 >= ce) return;
  const int n0 = (w & 7) * BN;

  __shared__ f16 lsA1[BM * BK];        // [128 row][4 chunk][8], 8 KB single-buf
  __shared__ f16 lsA2[BM * BK];
  __shared__ f16 lsW1[2][BN * BK];     // [4 kc][256 row][8], 2 x 16 KB dbuf
  __shared__ f16 lsW2[2][BN * BK];

  const int tid = threadIdx.x;   // 0..255

  const int ar0 = tid >> 2;            // 0..63
  const int gc  = (tid & 3) ^ ((ar0 >> 1) & 3);
  const size_t aofs0 = (size_t)tok[e * T_TOK + min(m0 + ar0,      ce - 1)] * DIM + gc * 8;
  const size_t aofs1 = (size_t)tok[e * T_TOK + min(m0 + ar0 + 64, ce - 1)] * DIM + gc * 8;
  const size_t wbase = (size_t)e * (DIM / 8) * DIM * 8 + ((size_t)n0 + tid) * 8;

  auto stageA = [&](int kt) {
    const int k0 = kt * BK;
    __builtin_amdgcn_global_load_lds(
        (const __attribute__((address_space(1))) void*)(A1 + aofs0 + k0),
        (__attribute__((address_space(3))) void*)(&lsA1[tid * 8]), 16, 0, 0);
    __builtin_amdgcn_global_load_lds(
        (const __attribute__((address_space(1))) void*)(A1 + aofs1 + k0),
        (__attribute__((address_space(3))) void*)(&lsA1[(tid + 256) * 8]), 16, 0, 0);
    __builtin_amdgcn_global_load_lds(
        (const __attribute__((address_space(1))) void*)(A2 + aofs0 + k0),
        (__attribute__((address_space(3))) void*)(&lsA2[tid * 8]), 16, 0, 0);
    __builtin_amdgcn_global_load_lds(
        (const __attribute__((address_space(1))) void*)(A2 + aofs1 + k0),
        (__attribute__((address_space(3))) void*)(&lsA2[(tid + 256) * 8]), 16, 0, 0);
  };
  auto stageW = [&](int kt, int bb) {
    const int kc0 = kt * 4;
#pragma unroll
    for (int j = 0; j < 4; ++j) {
      __builtin_amdgcn_global_load_lds(
          (const __attribute__((address_space(1))) void*)(W1t + wbase + (size_t)(kc0 + j) * DIM * 8),
          (__attribute__((address_space(3))) void*)(&lsW1[bb][(tid + 256 * j) * 8]), 16, 0, 0);
      __builtin_amdgcn_global_load_lds(
          (const __attribute__((address_space(1))) void*)(W2t + wbase + (size_t)(kc0 + j) * DIM * 8),
          (__attribute__((address_space(3))) void*)(&lsW2[bb][(tid + 256 * j) * 8]), 16, 0, 0);
    }
  };

  const int lane = tid & 63;
  const int wid  = tid >> 6;
  const int wm   = wid & 1;           // M half (64 rows)
  const int wn   = wid >> 1;          // N half (128 cols)
  const int lr   = lane & 15;
  const int lk   = lane >> 4;         // 0..3 -> k-chunk
  const int aswz = lk ^ ((lr >> 1) & 3);  // phys chunk holding logical lk

  f32x4 acc[4][8];
#pragma unroll
  for (int i = 0; i < 4; ++i)
#pragma unroll
    for (int j = 0; j < 8; ++j)
      acc[i][j] = (f32x4){0.f, 0.f, 0.f, 0.f};

  stageA(0);
  stageW(0, 0);
  asm volatile("s_waitcnt vmcnt(0)" ::: "memory");
  __builtin_amdgcn_s_barrier();
  __builtin_amdgcn_sched_barrier(0);

  int cur = 0;
  for (int kt = 0; kt < NT; ++kt) {
    const bool pf = (kt + 1 < NT);
    f16x8 a1F[4], a2F[4], w1F[8], w2F[8];

    // ---- (1) issue next-tile W stage first: its loads land under this kt
    if (pf) stageW(kt + 1, cur ^ 1);
    __builtin_amdgcn_sched_barrier(0);

    // ---- A frag reads (issued FIRST; DS retires in order)
#pragma unroll
    for (int mi = 0; mi < 4; ++mi) {
      int r = wm * 64 + mi * 16 + lr;
      a1F[mi] = *(const f16x8*)&lsA1[r * 32 + aswz * 8];
      a2F[mi] = *(const f16x8*)&lsA2[r * 32 + aswz * 8];
    }
    __builtin_amdgcn_sched_barrier(0);
    // ---- W1 frag reads (issued second; may stay in flight across barrier)
#pragma unroll
    for (int ni = 0; ni < 8; ++ni) {
      int off = (lk * 256 + wn * 128 + ni * 16 + lr) * 8;
      w1F[ni] = *(const f16x8*)&lsW1[cur][off];
    }
    // ---- (2) counted wait: only A reads (oldest 8) guard the barrier
    asm volatile("s_waitcnt lgkmcnt(8)" ::: "memory");
    __builtin_amdgcn_sched_barrier(0);
    __builtin_amdgcn_s_barrier();                        // lsA free
    __builtin_amdgcn_sched_barrier(0);
    if (pf) stageA(kt + 1);

    // w2F reads ride under clusters 0-1 (dbuf'd W; compiler inserts waits)
#pragma unroll
    for (int ni = 0; ni < 8; ++ni) {
      int off = (lk * 256 + wn * 128 + ni * 16 + lr) * 8;
      w2F[ni] = *(const f16x8*)&lsW2[cur][off];
    }

    __builtin_amdgcn_s_setprio(1);
#pragma unroll
    for (int mi = 0; mi < 4; ++mi)
#pragma unroll
      for (int ni = 0; ni < 8; ++ni)
        acc[mi][ni] = __builtin_amdgcn_mfma_f32_16x16x32_f16(a1F[mi], w1F[ni], acc[mi][ni], 0, 0, 0);
#pragma unroll
    for (int mi = 0; mi < 4; ++mi)
#pragma unroll
      for (int ni = 0; ni < 8; ++ni)
        acc[mi][ni] = __builtin_amdgcn_mfma_f32_16x16x32_f16(a2F[mi], w1F[ni], acc[mi][ni], 0, 0, 0);
#pragma unroll
    for (int mi = 0; mi < 4; ++mi)
#pragma unroll
      for (int ni = 0; ni < 8; ++ni)
        acc[mi][ni] = __builtin_amdgcn_mfma_f32_16x16x32_f16(a1F[mi], w2F[ni], acc[mi][ni], 0, 0, 0);
    __builtin_amdgcn_s_setprio(0);

    if (pf) {
      asm volatile("s_waitcnt vmcnt(0)" ::: "memory");   // mostly just the 4 A loads
      __builtin_amdgcn_s_barrier();
      __builtin_amdgcn_sched_barrier(0);
    }
    cur ^= 1;
  }

  // epilogue: out[tok, n] += w * acc / 4096  (descale 64*64)
  const int ebase = e * T_TOK;
#pragma unroll
  for (int mi = 0; mi < 4; ++mi) {
#pragma unroll
    for (int q = 0; q < 4; ++q) {
      int pos = m0 + wm * 64 + mi * 16 + lk * 4 + q;
      if (pos < ce) {
        int tt = tok[ebase + pos];
        float sc = wt[ebase + pos] * (1.0f / 4096.0f);
        float* orow = out + (size_t)tt * DIM + n0 + wn * 128;
#pragma unroll
        for (int ni = 0; ni < 8; ++ni)
          atomicAdd(&orow[ni * 16 + lr], sc * acc[mi][ni][q]);
      }
    }
  }
}

// --- 1-term GEMM (final layer), 128x128, 3 blocks/CU (R16 body, measured) ---
__global__ __launch_bounds__(256, 3) void moe_gemm1(
    const f16* __restrict__ A1,
    const f16* __restrict__ W1t,
    const int* __restrict__ tok, const float* __restrict__ wt,
    const int* __restrict__ cnt, float* __restrict__ out)
{
  const int b  = blockIdx.x;
  const int w  = (b >> 9) * 8 + (b & 7);   // 0..255
  const int my = (b >> 3) & 63;            // 0..63
  const int e  = w >> 4;
  const int ce = cnt[e];
  const int m0 = my * BM;
  if (m0 >= ce) return;
  const int n0 = (w & 15) * 128;

  __shared__ f16 lsA1[BM * BK];        // 8 KB single-buf, row-major
  __shared__ f16 lsW1[2][128 * BK];    // [4 kc][128 row][8], 2 x 8 KB dbuf

  const int tid = threadIdx.x;
  const int ar0 = tid >> 2;
  const int gc  = (tid & 3) ^ ((ar0 >> 1) & 3);
  const size_t aofs0 = (size_t)tok[e * T_TOK + min(m0 + ar0,      ce - 1)] * DIM + gc * 8;
  const size_t aofs1 = (size_t)tok[e * T_TOK + min(m0 + ar0 + 64, ce - 1)] * DIM + gc * 8;
  const int wrow = tid & 127;
  const int wkc  = tid >> 7;           // 0..1; slot1 kc += 2
  const size_t wbase = (size_t)e * (DIM / 8) * DIM * 8 + ((size_t)n0 + wrow) * 8;

  auto stageA = [&](int kt) {
    const int k0 = kt * BK;
    __builtin_amdgcn_global_load_lds(
        (const __attribute__((address_space(1))) void*)(A1 + aofs0 + k0),
        (__attribute__((address_space(3))) void*)(&lsA1[tid * 8]), 16, 0, 0);
    __builtin_amdgcn_global_load_lds(
        (const __attribute__((address_space(1))) void*)(A1 + aofs1 + k0),
        (__attribute__((address_space(3))) void*)(&lsA1[(tid + 256) * 8]), 16, 0, 0);
  };
  auto stageW = [&](int kt, int bb) {
    const int kc0 = kt * 4;
    __builtin_amdgcn_global_load_lds(
        (const __attribute__((address_space(1))) void*)(W1t + wbase + (size_t)(kc0 + wkc) * DIM * 8),
        (__attribute__((address_space(3))) void*)(&lsW1[bb][tid * 8]), 16, 0, 0);
    __builtin_amdgcn_global_load_lds(
        (const __attribute__((address_space(1))) void*)(W1t + wbase + (size_t)(kc0 + wkc + 2) * DIM * 8),
        (__attribute__((address_space(3))) void*)(&lsW1[bb][(tid + 256) * 8]), 16, 0, 0);
  };

  const int lane = tid & 63;
  const int wid  = tid >> 6;
  const int wm   = wid & 1;           // M half (64 rows)
  const int wn   = wid >> 1;          // N half (64 cols)
  const int lr   = lane & 15;
  const int lk   = lane >> 4;
  const int aswz = lk ^ ((lr >> 1) & 3);

  f32x4 acc[4][4];
#pragma unroll
  for (int i = 0; i < 4; ++i)
#pragma unroll
    for (int j = 0; j < 4; ++j)
      acc[i][j] = (f32x4){0.f, 0.f, 0.f, 0.f};

  stageA(0);
  stageW(0, 0);
  asm volatile("s_waitcnt vmcnt(0)" ::: "memory");
  __builtin_amdgcn_s_barrier();
  __builtin_amdgcn_sched_barrier(0);

  int cur = 0;
  for (int kt = 0; kt < NT; ++kt) {
    const bool pf = (kt + 1 < NT);
    f16x8 a1F[4], w1F[4];

#pragma unroll
    for (int mi = 0; mi < 4; ++mi) {
      int r = wm * 64 + mi * 16 + lr;
      a1F[mi] = *(const f16x8*)&lsA1[r * 32 + aswz * 8];
    }
#pragma unroll
    for (int ni = 0; ni < 4; ++ni) {
      int off = (lk * 128 + wn * 64 + ni * 16 + lr) * 8;
      w1F[ni] = *(const f16x8*)&lsW1[cur][off];
    }
    asm volatile("s_waitcnt lgkmcnt(0)" ::: "memory");
    __builtin_amdgcn_sched_barrier(0);
    __builtin_amdgcn_s_barrier();
    __builtin_amdgcn_sched_barrier(0);
    if (pf) { stageA(kt + 1); stageW(kt + 1, cur ^ 1); }

    __builtin_amdgcn_s_setprio(1);
#pragma unroll
    for (int mi = 0; mi < 4; ++mi)
#pragma unroll
      for (int ni = 0; ni < 4; ++ni)
        acc[mi][ni] = __builtin_amdgcn_mfma_f32_16x16x32_f16(a1F[mi], w1F[ni], acc[mi][ni], 0, 0, 0);
    __builtin_amdgcn_s_setprio(0);

    if (pf) {
      asm volatile("s_waitcnt vmcnt(0)" ::: "memory");
      __builtin_amdgcn_s_barrier();
      __builtin_amdgcn_sched_barrier(0);
    }
    cur ^= 1;
  }

  const int ebase = e * T_TOK;
#pragma unroll
  for (int mi = 0; mi < 4; ++mi) {
#pragma unroll
    for (int q = 0; q < 4; ++q) {
      int pos = m0 + wm * 64 + mi * 16 + lk * 4 + q;
      if (pos < ce) {
        int tt = tok[ebase + pos];
        float sc = wt[ebase + pos] * (1.0f / 4096.0f);
        float* orow = out + (size_t)tt * DIM + n0 + wn * 64;
#pragma unroll
        for (int ni = 0; ni < 4; ++ni)
          atomicAdd(&orow[ni * 16 + lr], sc * acc[mi][ni][q]);
      }
    }
  }
}

// ------------------------------- launcher -----------------------------------
extern "C" void kernel_launch(void* const* d_in, const int* in_sizes, int n_in,
                              void* d_out, int out_size, void* d_ws, size_t ws_size,
                              hipStream_t stream) {
  const float* x  = (const float*)d_in[0];
  const float* gw = (const float*)d_in[1];
  const float* ew = (const float*)d_in[2];
  float* out = (float*)d_out;

  char* ws = (char*)d_ws;
  float* hA  = (float*)ws;                        // 64 MB fp32 h ping buffer
  f16*   A1  = (f16*)(ws + 67108864ull);          // 32 MB
  f16*   A2  = (f16*)(ws + 100663296ull);         // 32 MB
  f16*   W1t = (f16*)(ws + 134217728ull);         // 128 MB (K-major, this layer)
  f16*   W2t = (f16*)(ws + 268435456ull);         // 128 MB
  int*   tok = (int*)(ws + 402653184ull);         // 512 KB
  float* wt  = (float*)(ws + 403177472ull);       // 512 KB
  int*   cnt = (int*)(ws + 403701760ull);         // 64 B

  const float* hin = x;
  float* houts[4] = {hA, out, hA, out};           // ping-pong; final layer -> d_out
  for (int l = 0; l < NLAY; ++l) {
    float* hout = houts[l];
    hipMemsetAsync(cnt, 0, 64, stream);
    route_kernel<<<T_TOK / 4, 256, 0, stream>>>(hin, gw + (size_t)l * NEXP * DIM, cnt, tok, wt);
    split_kernel<<<4096, 256, 0, stream>>>(hin, A1, A2, T_TOK * DIM / 4);
    {
      dim3 gt(DIM / 64, DIM / 32, NEXP);
      wsplit_kernel<<<gt, 256, 0, stream>>>(ew + (size_t)l * NEXP * DIM * DIM, W1t, W2t);
    }
    hipMemsetAsync(hout, 0, (size_t)T_TOK * DIM * 4, stream);
    if (l < NLAY - 1)
      moe_gemm3<<<16 * 64 * 8, 256, 0, stream>>>(A1, A2, W1t, W2t, tok, wt, cnt, hout);
    else
      moe_gemm1<<<16 * 64 * 16, 256, 0, stream>>>(A1, W1t, tok, wt, cnt, hout);
    hin = hout;
  }
}